// Round 5
// baseline (972.208 us; speedup 1.0000x reference)
//
#include <hip/hip_runtime.h>
#include <hip/hip_bf16.h>
#include <cmath>

typedef __hip_bfloat16 bf16;
typedef float v4f __attribute__((ext_vector_type(4)));
typedef short v8s __attribute__((ext_vector_type(8)));   // 8 x bf16 bits

__device__ __forceinline__ v4f mfma16x16x32(v8s a, v8s b, v4f c) {
  return __builtin_amdgcn_mfma_f32_16x16x32_bf16(a, b, c, 0, 0, 0);
}
__device__ __forceinline__ float b2f(bf16 x) { return __bfloat162float(x); }
__device__ __forceinline__ bf16 f2b(float x) { return __float2bfloat16(x); }
__device__ __forceinline__ float gelu_exact(float x) {
  return 0.5f * x * (1.0f + erff(x * 0.70710678118654752f));
}
// non-finite -> stage sentinel (diagnostic channel through absmax)
__device__ __forceinline__ float finz(float v, float sent) {
  return __builtin_isfinite(v) ? v : sent;
}
__device__ __forceinline__ float u2f(ushort u) {
  return __uint_as_float(((unsigned)u) << 16);
}

// generic 4-element load -> float4
__device__ __forceinline__ float4 load4f(const float* p) {
  return *(const float4*)p;
}
__device__ __forceinline__ float4 load4f(const bf16* p) {
  ushort4 u = *(const ushort4*)p;
  return make_float4(u2f(u.x), u2f(u.y), u2f(u.z), u2f(u.w));
}

// ---------------------------------------------------------------------------
// LayerNorm: one block per row of 1024, 256 threads x 4 elems, fp32 stats.
// TI = float (x) or bf16 (x1). Output bf16.
// ---------------------------------------------------------------------------
template <typename TI>
__global__ __launch_bounds__(256)
void ln_kernel(const TI* __restrict__ x, const float* __restrict__ g,
               const float* __restrict__ b, bf16* __restrict__ out) {
  __shared__ float red[8];
  __shared__ float stat[2];
  const int row = blockIdx.x, t = threadIdx.x;
  const int wave = t >> 6, lane = t & 63;
  float4 v = load4f(x + (long)row * 1024 + t * 4);
  float s = v.x + v.y + v.z + v.w;
  float s2 = v.x * v.x + v.y * v.y + v.z * v.z + v.w * v.w;
#pragma unroll
  for (int off = 32; off > 0; off >>= 1) {
    s += __shfl_down(s, off);
    s2 += __shfl_down(s2, off);
  }
  if (lane == 0) { red[wave * 2] = s; red[wave * 2 + 1] = s2; }
  __syncthreads();
  if (t == 0) {
    float S = red[0] + red[2] + red[4] + red[6];
    float S2 = red[1] + red[3] + red[5] + red[7];
    float mean = S * (1.0f / 1024.0f);
    float var = S2 * (1.0f / 1024.0f) - mean * mean;
    stat[0] = mean;
    stat[1] = rsqrtf(var + 1e-5f);
  }
  __syncthreads();
  const float mean = stat[0], rs = stat[1];
  bf16* orow = out + (long)row * 1024;
  const int c = t * 4;
  float4 gg = *(const float4*)(g + c);
  float4 bb = *(const float4*)(b + c);
  orow[c + 0] = f2b(finz((v.x - mean) * rs * gg.x + bb.x, 3000.f));
  orow[c + 1] = f2b(finz((v.y - mean) * rs * gg.y + bb.y, 3000.f));
  orow[c + 2] = f2b(finz((v.z - mean) * rs * gg.z + bb.z, 3000.f));
  orow[c + 3] = f2b(finz((v.w - mean) * rs * gg.w + bb.w, 3000.f));
}

// ---------------------------------------------------------------------------
// Repack Wq/Wk/Wv fp32 [H=16, D=1024, HD=64] -> bf16 Wt[n=h*64+kk][d]
// ---------------------------------------------------------------------------
__global__ __launch_bounds__(256)
void repack_qkv(const float* __restrict__ w, bf16* __restrict__ wt) {
  long i = (long)blockIdx.x * 256 + threadIdx.x;  // over 1M outputs
  int n = (int)(i >> 10), d = (int)(i & 1023);
  int h = n >> 6, kk = n & 63;
  wt[i] = f2b(w[((long)h * 1024 + d) * 64 + kk]);
}

// ---------------------------------------------------------------------------
// Tiled transpose fp32 -> bf16: out[c*R + r] = in[r*C + c]
// ---------------------------------------------------------------------------
__global__ __launch_bounds__(256)
void transpose_f2b(const float* __restrict__ in, bf16* __restrict__ out,
                   int R, int C) {
  __shared__ float tile[32][33];
  const int tx = threadIdx.x & 31, ty = threadIdx.x >> 5;
  const int r0 = blockIdx.y * 32, c0 = blockIdx.x * 32;
#pragma unroll
  for (int i = ty; i < 32; i += 8) tile[i][tx] = in[(long)(r0 + i) * C + c0 + tx];
  __syncthreads();
#pragma unroll
  for (int i = ty; i < 32; i += 8)
    out[(long)(c0 + i) * R + r0 + tx] = f2b(tile[tx][i]);
}

// ---------------------------------------------------------------------------
// GEMM C[M,N] = A[M,K] @ Bt[N,K]^T  (128x128 tile, BK=32, register staging)
// A, Bt bf16; biases fp32.
// EPI: 0 = +bias                      -> bf16 C0 (FFN mid,  sentinel 4e4)
//      1 = +bias + fp32 resid         -> bf16 C0 (x1,       sentinel 2e4)
//      2 = gelu(+bias) + bf16 resid   -> FP32 C0 (final,    sentinel 1e5)
//      3 = QKV scatter + per-proj bias-> bf16 C0/C1/C2      (sentinel 1e4)
// ---------------------------------------------------------------------------
template <int EPI>
__global__ __launch_bounds__(256)
void gemm_bt(const bf16* __restrict__ A, const bf16* __restrict__ Bt,
             const float* __restrict__ bias0, const float* __restrict__ bias1,
             const float* __restrict__ bias2, const void* __restrict__ residv,
             void* __restrict__ C0v, bf16* __restrict__ C1, bf16* __restrict__ C2v,
             int M, int N, int K) {
  __shared__ bf16 As[128 * 32];
  __shared__ bf16 Bs[128 * 32];
  const int t = threadIdx.x;
  const int wave = t >> 6, lane = t & 63, quad = lane >> 4, ln = lane & 15;
  const int m0 = blockIdx.y * 128, n0 = blockIdx.x * 128;
  const int wm = (wave >> 1) * 64, wn = (wave & 1) * 64;

  v4f acc[4][4];
#pragma unroll
  for (int i = 0; i < 4; i++)
#pragma unroll
    for (int j = 0; j < 4; j++) acc[i][j] = v4f{0.f, 0.f, 0.f, 0.f};

  const int e0 = t * 8, e1 = t * 8 + 2048;
  const int ra0 = e0 >> 5, ca0 = e0 & 31, ra1 = e1 >> 5, ca1 = e1 & 31;
  const bf16* Ab = A + (long)m0 * K;
  const bf16* Bb = Bt + (long)n0 * K;

  for (int k0 = 0; k0 < K; k0 += 32) {
    v8s a0 = *(const v8s*)(Ab + (long)ra0 * K + k0 + ca0);
    v8s a1 = *(const v8s*)(Ab + (long)ra1 * K + k0 + ca1);
    v8s bb0 = *(const v8s*)(Bb + (long)ra0 * K + k0 + ca0);
    v8s bb1 = *(const v8s*)(Bb + (long)ra1 * K + k0 + ca1);
    __syncthreads();  // previous iteration's fragment reads complete
    *(v8s*)&As[e0] = a0;
    *(v8s*)&As[e1] = a1;
    *(v8s*)&Bs[e0] = bb0;
    *(v8s*)&Bs[e1] = bb1;
    __syncthreads();  // staging visible to all waves
    v8s af[4], bfr[4];
#pragma unroll
    for (int mi = 0; mi < 4; mi++)
      af[mi] = *(const v8s*)&As[(wm + mi * 16 + ln) * 32 + quad * 8];
#pragma unroll
    for (int ni = 0; ni < 4; ni++)
      bfr[ni] = *(const v8s*)&Bs[(wn + ni * 16 + ln) * 32 + quad * 8];
#pragma unroll
    for (int mi = 0; mi < 4; mi++)
#pragma unroll
      for (int ni = 0; ni < 4; ni++)
        acc[mi][ni] = mfma16x16x32(af[mi], bfr[ni], acc[mi][ni]);
  }

#pragma unroll
  for (int ni = 0; ni < 4; ni++) {
    const int col = n0 + wn + ni * 16 + ln;
    if (EPI == 3) {
      const int proj = col >> 10, w = col & 1023;
      const float* bp = proj == 0 ? bias0 : (proj == 1 ? bias1 : bias2);
      bf16* op = proj == 0 ? (bf16*)C0v : (proj == 1 ? C1 : C2v);
      const float bb = bp[w];
      const int hidx = w >> 6, hd = w & 63;
#pragma unroll
      for (int mi = 0; mi < 4; mi++)
#pragma unroll
        for (int r = 0; r < 4; r++) {
          const int row = m0 + wm + mi * 16 + quad * 4 + r;  // = b*2048 + s
          const int b_ = row >> 11, s = row & 2047;
          op[(((long)(b_ * 16 + hidx)) * 2048 + s) * 64 + hd] =
              f2b(finz(acc[mi][ni][r] + bb, 1e4f));
        }
    } else {
      const float bb = bias0[col];
#pragma unroll
      for (int mi = 0; mi < 4; mi++)
#pragma unroll
        for (int r = 0; r < 4; r++) {
          const int row = m0 + wm + mi * 16 + quad * 4 + r;
          float vv = acc[mi][ni][r] + bb;
          if (EPI == 2) {
            vv = gelu_exact(vv);
            vv += b2f(((const bf16*)residv)[(long)row * N + col]);
            // final output is FP32 (reference computes in fp32)
            ((float*)C0v)[(long)row * N + col] = finz(vv, 1e5f);
          } else {
            if (EPI == 1) vv += ((const float*)residv)[(long)row * N + col];
            const float sent = EPI == 0 ? 4e4f : 2e4f;
            ((bf16*)C0v)[(long)row * N + col] = f2b(finz(vv, sent));
          }
        }
    }
  }
}

// ---------------------------------------------------------------------------
// Flash attention: grid (S/64, B*H); block 256 (4 waves); 64-row Q tile;
// online softmax with LDS round-trip (m120 pattern). q,k,v: [B,H,S,64] bf16.
// ---------------------------------------------------------------------------
__global__ __launch_bounds__(256)
void attn_kernel(const bf16* __restrict__ q, const bf16* __restrict__ k,
                 const bf16* __restrict__ v, bf16* __restrict__ o) {
  __shared__ bf16 Qs[64 * 64];
  __shared__ bf16 Ks[64 * 64];
  __shared__ bf16 Vt[64 * 64];  // transposed: Vt[hd][kv]
  __shared__ bf16 Pb[64 * 64];
  __shared__ float Sf[64 * 64];
  __shared__ float m_s[64], l_s[64], al_s[64];

  const int t = threadIdx.x, wave = t >> 6, lane = t & 63;
  const int quad = lane >> 4, ln = lane & 15;
  const int bh = blockIdx.y, q0 = blockIdx.x * 64;
  const long base = (long)bh * (2048 * 64);

  const int e0 = t * 8, e1 = t * 8 + 2048;
  {
    v8s q0v = *(const v8s*)(q + base + (long)q0 * 64 + e0);
    v8s q1v = *(const v8s*)(q + base + (long)q0 * 64 + e1);
    *(v8s*)&Qs[e0] = q0v;
    *(v8s*)&Qs[e1] = q1v;
  }
  if (t < 64) { m_s[t] = -1e30f; l_s[t] = 0.f; al_s[t] = 0.f; }

  v4f accO[4];
#pragma unroll
  for (int i = 0; i < 4; i++) accO[i] = v4f{0.f, 0.f, 0.f, 0.f};
  const float scale = 0.125f;  // 1/sqrt(64)

  for (int kv0 = 0; kv0 < 2048; kv0 += 64) {
    v8s k0v = *(const v8s*)(k + base + (long)kv0 * 64 + e0);
    v8s k1v = *(const v8s*)(k + base + (long)kv0 * 64 + e1);
    __syncthreads();  // previous iteration's LDS reads complete
    *(v8s*)&Ks[e0] = k0v;
    *(v8s*)&Ks[e1] = k1v;
    {
      const ushort* gv = (const ushort*)(v + base + (long)kv0 * 64);
#pragma unroll
      for (int c = 0; c < 2; c++) {
        const int e = t * 8 + c * 2048;
        const int kvr = e >> 6, hd0 = e & 63;
        ushort4 p0 = *(const ushort4*)(gv + e);
        ushort4 p1 = *(const ushort4*)(gv + e + 4);
        ushort vals[8] = {p0.x, p0.y, p0.z, p0.w, p1.x, p1.y, p1.z, p1.w};
#pragma unroll
        for (int j = 0; j < 8; j++)
          ((ushort*)Vt)[(hd0 + j) * 64 + kvr] = vals[j];
      }
    }
    __syncthreads();

    // S = Q @ K^T  (each wave: 16 q-rows x 64 keys)
    v8s aq0 = *(const v8s*)&Qs[(wave * 16 + ln) * 64 + quad * 8];
    v8s aq1 = *(const v8s*)&Qs[(wave * 16 + ln) * 64 + 32 + quad * 8];
#pragma unroll
    for (int ni = 0; ni < 4; ni++) {
      v8s b0 = *(const v8s*)&Ks[(ni * 16 + ln) * 64 + quad * 8];
      v8s b1 = *(const v8s*)&Ks[(ni * 16 + ln) * 64 + 32 + quad * 8];
      v4f s4 = v4f{0.f, 0.f, 0.f, 0.f};
      s4 = mfma16x16x32(aq0, b0, s4);
      s4 = mfma16x16x32(aq1, b1, s4);
#pragma unroll
      for (int r = 0; r < 4; r++)
        Sf[(wave * 16 + quad * 4 + r) * 64 + ni * 16 + ln] = s4[r] * scale;
    }
    __syncthreads();

    // online softmax: 4 threads per row, 16 cols each
    {
      const int row = t >> 2, seg = t & 3;
      float sv[16], mx = -1e30f;
#pragma unroll
      for (int j = 0; j < 16; j++) {
        sv[j] = Sf[row * 64 + seg * 16 + j];
        mx = fmaxf(mx, sv[j]);
      }
      mx = fmaxf(mx, __shfl_xor(mx, 1));
      mx = fmaxf(mx, __shfl_xor(mx, 2));
      const float mo = m_s[row];
      const float mn = fmaxf(mo, mx);
      float sum = 0.f;
#pragma unroll
      for (int j = 0; j < 16; j++) {
        float p = __expf(sv[j] - mn);
        sum += p;
        Pb[row * 64 + seg * 16 + j] = f2b(p);
      }
      sum += __shfl_xor(sum, 1);
      sum += __shfl_xor(sum, 2);
      if (seg == 0) {
        m_s[row] = mn;
        l_s[row] = l_s[row] * __expf(mo - mn) + sum;
        al_s[row] = __expf(mo - mn);
      }
    }
    __syncthreads();

    // O = O*alpha + P @ V
    float al4[4];
#pragma unroll
    for (int r = 0; r < 4; r++) al4[r] = al_s[wave * 16 + quad * 4 + r];
#pragma unroll
    for (int ni = 0; ni < 4; ni++)
#pragma unroll
      for (int r = 0; r < 4; r++) accO[ni][r] *= al4[r];
    v8s ap0 = *(const v8s*)&Pb[(wave * 16 + ln) * 64 + quad * 8];
    v8s ap1 = *(const v8s*)&Pb[(wave * 16 + ln) * 64 + 32 + quad * 8];
#pragma unroll
    for (int ni = 0; ni < 4; ni++) {
      v8s b0 = *(const v8s*)&Vt[(ni * 16 + ln) * 64 + quad * 8];
      v8s b1 = *(const v8s*)&Vt[(ni * 16 + ln) * 64 + 32 + quad * 8];
      accO[ni] = mfma16x16x32(ap0, b0, accO[ni]);
      accO[ni] = mfma16x16x32(ap1, b1, accO[ni]);
    }
  }
  __syncthreads();

  const int b_ = bh >> 4, h_ = bh & 15;
#pragma unroll
  for (int r = 0; r < 4; r++) {
    const int s = q0 + wave * 16 + quad * 4 + r;
    const float inv = 1.f / l_s[wave * 16 + quad * 4 + r];
#pragma unroll
    for (int ni = 0; ni < 4; ni++) {
      const int hd = ni * 16 + ln;
      o[((long)(b_ * 2048 + s)) * 1024 + h_ * 64 + hd] =
          f2b(finz(accO[ni][r] * inv, 5000.f));
    }
  }
}

// ---------------------------------------------------------------------------
extern "C" void kernel_launch(void* const* d_in, const int* in_sizes, int n_in,
                              void* d_out, int out_size, void* d_ws,
                              size_t ws_size, hipStream_t stream) {
  // Inputs fp32 (reference dtype); OUTPUT fp32 (reference returns fp32).
  const float* x   = (const float*)d_in[0];
  const float* Wq  = (const float*)d_in[1];
  const float* bq  = (const float*)d_in[2];
  const float* Wk  = (const float*)d_in[3];
  const float* bk  = (const float*)d_in[4];
  const float* Wv  = (const float*)d_in[5];
  const float* bv  = (const float*)d_in[6];
  const float* Wo  = (const float*)d_in[7];
  const float* bo  = (const float*)d_in[8];
  const float* W1  = (const float*)d_in[9];
  const float* b1  = (const float*)d_in[10];
  const float* W2  = (const float*)d_in[11];
  const float* b2  = (const float*)d_in[12];
  const float* g1  = (const float*)d_in[13];
  const float* be1 = (const float*)d_in[14];
  const float* g2  = (const float*)d_in[15];
  const float* be2 = (const float*)d_in[16];
  float* out = (float*)d_out;

  // ws layout, byte offsets. Peak footprint = 104 MB (round-3 guard passed
  // => ws >= 104 MB). Guard: too-small ws -> no-op (absmax 6.65-ish diag).
  const size_t MB = 1024 * 1024;
  if (ws_size < 104 * MB) return;
  char* W = (char*)d_ws;
  bf16* wqt = (bf16*)(W + 0 * MB);    // [0,6)  wq/wk/wv rows contig [3072][1024]
  bf16* wkt = (bf16*)(W + 2 * MB);
  bf16* wvt = (bf16*)(W + 4 * MB);
  bf16* wot = (bf16*)(W + 6 * MB);    // [6,8)
  bf16* h   = (bf16*)(W + 8 * MB);    // [8,24)   LN1 out; later LN2 out
  bf16* qb  = (bf16*)(W + 24 * MB);   // [24,40)  dead after attn
  bf16* kb  = (bf16*)(W + 40 * MB);   // [40,56)  dead after attn
  bf16* vb  = (bf16*)(W + 56 * MB);   // [56,72)  dead after attn
  bf16* ao  = (bf16*)(W + 72 * MB);   // [72,88)  dead after Wo-gemm
  bf16* x1  = (bf16*)(W + 88 * MB);   // [88,104) live to end
  bf16* w1t = (bf16*)(W + 24 * MB);   // [24,32)  after attn (qb slot)
  bf16* w2t = (bf16*)(W + 32 * MB);   // [32,40)
  bf16* tbc = (bf16*)(W + 40 * MB);   // [40,72)  FFN mid chunk [4096][4096]

  // weight repacks needed through step 4 (fp32 -> bf16, B^T layout)
  repack_qkv<<<4096, 256, 0, stream>>>(Wq, wqt);
  repack_qkv<<<4096, 256, 0, stream>>>(Wk, wkt);
  repack_qkv<<<4096, 256, 0, stream>>>(Wv, wvt);
  transpose_f2b<<<dim3(32, 32), 256, 0, stream>>>(Wo, wot, 1024, 1024);

  // 1) h = LN1(x)
  ln_kernel<float><<<8192, 256, 0, stream>>>(x, g1, be1, h);
  // 2) q,k,v = h @ Wqkv + b   (scatter to [B,H,S,64])
  gemm_bt<3><<<dim3(24, 64), 256, 0, stream>>>(h, wqt, bq, bk, bv, nullptr,
                                               qb, kb, vb, 8192, 3072, 1024);
  // 3) flash attention -> ao [B,S,D]
  attn_kernel<<<dim3(32, 64), 256, 0, stream>>>(qb, kb, vb, ao);
  // 4) x1 = x + ao @ Wo + bo   (fp32 resid x, bf16 x1 out)
  gemm_bt<1><<<dim3(8, 64), 256, 0, stream>>>(ao, wot, bo, nullptr, nullptr, x,
                                              x1, nullptr, nullptr, 8192, 1024, 1024);
  // FFN weights into freed q/k slots (must be after attn)
  transpose_f2b<<<dim3(128, 32), 256, 0, stream>>>(W1, w1t, 1024, 4096);
  transpose_f2b<<<dim3(32, 128), 256, 0, stream>>>(W2, w2t, 4096, 1024);
  // 5) h2 = LN2(x1)  (bf16-in variant, into h slot)
  ln_kernel<bf16><<<8192, 256, 0, stream>>>(x1, g2, be2, h);
  // 6/7) FFN, M-chunked (2 x 4096 rows), mid buffer 32 MB; final out FP32
  for (int c = 0; c < 2; c++) {
    const long moff = (long)c * 4096 * 1024;
    gemm_bt<0><<<dim3(32, 32), 256, 0, stream>>>(h + moff, w1t, b1, nullptr,
                                                 nullptr, nullptr, tbc, nullptr,
                                                 nullptr, 4096, 4096, 1024);
    gemm_bt<2><<<dim3(8, 32), 256, 0, stream>>>(tbc, w2t, b2, nullptr, nullptr,
                                                x1 + moff, out + moff, nullptr,
                                                nullptr, 4096, 1024, 4096);
  }
}

// Round 6
// 869.495 us; speedup vs baseline: 1.1181x; 1.1181x over previous
//
#include <hip/hip_runtime.h>
#include <hip/hip_bf16.h>
#include <cmath>

typedef __hip_bfloat16 bf16;
typedef float v4f __attribute__((ext_vector_type(4)));
typedef short v8s __attribute__((ext_vector_type(8)));   // 8 x bf16 bits

__device__ __forceinline__ void load_lds16(const void* g, void* l) {
  __builtin_amdgcn_global_load_lds(
      (const __attribute__((address_space(1))) char*)g,
      (__attribute__((address_space(3))) char*)l, 16, 0, 0);
}
__device__ __forceinline__ v4f mfma16x16x32(v8s a, v8s b, v4f c) {
  return __builtin_amdgcn_mfma_f32_16x16x32_bf16(a, b, c, 0, 0, 0);
}
__device__ __forceinline__ float b2f(bf16 x) { return __bfloat162float(x); }
__device__ __forceinline__ bf16 f2b(float x) { return __float2bfloat16(x); }
__device__ __forceinline__ ushort b2u(float x) {
  bf16 h = f2b(x);
  return *(ushort*)&h;
}
__device__ __forceinline__ float gelu_exact(float x) {
  return 0.5f * x * (1.0f + erff(x * 0.70710678118654752f));
}
__device__ __forceinline__ float finz(float v, float sent) {
  return __builtin_isfinite(v) ? v : sent;
}
__device__ __forceinline__ float u2f(ushort u) {
  return __uint_as_float(((unsigned)u) << 16);
}
__device__ __forceinline__ float4 load4f(const float* p) {
  return *(const float4*)p;
}
__device__ __forceinline__ float4 load4f(const bf16* p) {
  ushort4 u = *(const ushort4*)p;
  return make_float4(u2f(u.x), u2f(u.y), u2f(u.z), u2f(u.w));
}

// ---------------------------------------------------------------------------
// LayerNorm: one block per row of 1024, fp32 stats, bf16 out.
// ---------------------------------------------------------------------------
template <typename TI>
__global__ __launch_bounds__(256)
void ln_kernel(const TI* __restrict__ x, const float* __restrict__ g,
               const float* __restrict__ b, bf16* __restrict__ out) {
  __shared__ float red[8];
  __shared__ float stat[2];
  const int row = blockIdx.x, t = threadIdx.x;
  const int wave = t >> 6, lane = t & 63;
  float4 v = load4f(x + (long)row * 1024 + t * 4);
  float s = v.x + v.y + v.z + v.w;
  float s2 = v.x * v.x + v.y * v.y + v.z * v.z + v.w * v.w;
#pragma unroll
  for (int off = 32; off > 0; off >>= 1) {
    s += __shfl_down(s, off);
    s2 += __shfl_down(s2, off);
  }
  if (lane == 0) { red[wave * 2] = s; red[wave * 2 + 1] = s2; }
  __syncthreads();
  if (t == 0) {
    float S = red[0] + red[2] + red[4] + red[6];
    float S2 = red[1] + red[3] + red[5] + red[7];
    float mean = S * (1.0f / 1024.0f);
    float var = S2 * (1.0f / 1024.0f) - mean * mean;
    stat[0] = mean;
    stat[1] = rsqrtf(var + 1e-5f);
  }
  __syncthreads();
  const float mean = stat[0], rs = stat[1];
  bf16* orow = out + (long)row * 1024;
  const int c = t * 4;
  float4 gg = *(const float4*)(g + c);
  float4 bb = *(const float4*)(b + c);
  orow[c + 0] = f2b(finz((v.x - mean) * rs * gg.x + bb.x, 3000.f));
  orow[c + 1] = f2b(finz((v.y - mean) * rs * gg.y + bb.y, 3000.f));
  orow[c + 2] = f2b(finz((v.z - mean) * rs * gg.z + bb.z, 3000.f));
  orow[c + 3] = f2b(finz((v.w - mean) * rs * gg.w + bb.w, 3000.f));
}

// ---------------------------------------------------------------------------
// Repack Wq/Wk/Wv fp32 [H=16, D=1024, HD=64] -> bf16 Wt[n=h*64+kk][d]
// ---------------------------------------------------------------------------
__global__ __launch_bounds__(256)
void repack_qkv(const float* __restrict__ w, bf16* __restrict__ wt) {
  long i = (long)blockIdx.x * 256 + threadIdx.x;
  int n = (int)(i >> 10), d = (int)(i & 1023);
  int h = n >> 6, kk = n & 63;
  wt[i] = f2b(w[((long)h * 1024 + d) * 64 + kk]);
}

// ---------------------------------------------------------------------------
// Tiled transpose fp32 -> bf16: out[c*R + r] = in[r*C + c]
// ---------------------------------------------------------------------------
__global__ __launch_bounds__(256)
void transpose_f2b(const float* __restrict__ in, bf16* __restrict__ out,
                   int R, int C) {
  __shared__ float tile[32][33];
  const int tx = threadIdx.x & 31, ty = threadIdx.x >> 5;
  const int r0 = blockIdx.y * 32, c0 = blockIdx.x * 32;
#pragma unroll
  for (int i = ty; i < 32; i += 8) tile[i][tx] = in[(long)(r0 + i) * C + c0 + tx];
  __syncthreads();
#pragma unroll
  for (int i = ty; i < 32; i += 8)
    out[(long)(c0 + i) * R + r0 + tx] = f2b(tile[tx][i]);
}

// ---------------------------------------------------------------------------
// GEMM C[M,N] = A[M,K] @ Bt[N,K]^T (128x128, BK=32, async global_load_lds).
// EPI: 0=+bias (bf16)  1=+bias+fp32 resid (bf16)  2=gelu+bf16 resid (FP32)
//      3=QKV scatter: q,k -> [B,H,S,64]; v -> TRANSPOSED [B,H,64,S]
// ---------------------------------------------------------------------------
template <int EPI>
__global__ __launch_bounds__(256)
void gemm_bt(const bf16* __restrict__ A, const bf16* __restrict__ Bt,
             const float* __restrict__ bias0, const float* __restrict__ bias1,
             const float* __restrict__ bias2, const void* __restrict__ residv,
             void* __restrict__ C0v, bf16* __restrict__ C1, bf16* __restrict__ C2v,
             int M, int N, int K) {
  __shared__ bf16 As[128 * 32];
  __shared__ bf16 Bs[128 * 32];
  const int t = threadIdx.x;
  const int wave = t >> 6, lane = t & 63, quad = lane >> 4, ln = lane & 15;
  const int m0 = blockIdx.y * 128, n0 = blockIdx.x * 128;
  const int wm = (wave >> 1) * 64, wn = (wave & 1) * 64;

  v4f acc[4][4];
#pragma unroll
  for (int i = 0; i < 4; i++)
#pragma unroll
    for (int j = 0; j < 4; j++) acc[i][j] = v4f{0.f, 0.f, 0.f, 0.f};

  const int e0 = t * 8, e1 = t * 8 + 2048;
  const int ra0 = e0 >> 5, ca0 = e0 & 31, ra1 = e1 >> 5, ca1 = e1 & 31;
  const bf16* Ab = A + (long)m0 * K;
  const bf16* Bb = Bt + (long)n0 * K;

  for (int k0 = 0; k0 < K; k0 += 32) {
    __syncthreads();  // prior frag reads complete before restage
    load_lds16(Ab + (long)ra0 * K + k0 + ca0, &As[e0]);
    load_lds16(Ab + (long)ra1 * K + k0 + ca1, &As[e1]);
    load_lds16(Bb + (long)ra0 * K + k0 + ca0, &Bs[e0]);
    load_lds16(Bb + (long)ra1 * K + k0 + ca1, &Bs[e1]);
    __syncthreads();  // staging visible (vmcnt drained at barrier)
    v8s af[4], bfr[4];
#pragma unroll
    for (int mi = 0; mi < 4; mi++)
      af[mi] = *(const v8s*)&As[(wm + mi * 16 + ln) * 32 + quad * 8];
#pragma unroll
    for (int ni = 0; ni < 4; ni++)
      bfr[ni] = *(const v8s*)&Bs[(wn + ni * 16 + ln) * 32 + quad * 8];
#pragma unroll
    for (int mi = 0; mi < 4; mi++)
#pragma unroll
      for (int ni = 0; ni < 4; ni++)
        acc[mi][ni] = mfma16x16x32(af[mi], bfr[ni], acc[mi][ni]);
  }

#pragma unroll
  for (int ni = 0; ni < 4; ni++) {
    const int col = n0 + wn + ni * 16 + ln;
    if (EPI == 3) {
      const int proj = col >> 10, w = col & 1023;
      const float* bp = proj == 0 ? bias0 : (proj == 1 ? bias1 : bias2);
      const float bb = bp[w];
      const int hidx = w >> 6, hd = w & 63;
      if (proj == 2) {
        // v transposed: [b*16+h][hd][2048], ushort4-packed along s
#pragma unroll
        for (int mi = 0; mi < 4; mi++) {
          const int row0 = m0 + wm + mi * 16 + quad * 4;
          const int b_ = row0 >> 11, s = row0 & 2047;
          ushort4 pk;
          pk.x = b2u(finz(acc[mi][ni][0] + bb, 1e4f));
          pk.y = b2u(finz(acc[mi][ni][1] + bb, 1e4f));
          pk.z = b2u(finz(acc[mi][ni][2] + bb, 1e4f));
          pk.w = b2u(finz(acc[mi][ni][3] + bb, 1e4f));
          *(ushort4*)((ushort*)C2v +
                      (((long)(b_ * 16 + hidx)) * 64 + hd) * 2048 + s) = pk;
        }
      } else {
        bf16* op = proj == 0 ? (bf16*)C0v : C1;
#pragma unroll
        for (int mi = 0; mi < 4; mi++)
#pragma unroll
          for (int r = 0; r < 4; r++) {
            const int row = m0 + wm + mi * 16 + quad * 4 + r;
            const int b_ = row >> 11, s = row & 2047;
            op[(((long)(b_ * 16 + hidx)) * 2048 + s) * 64 + hd] =
                f2b(finz(acc[mi][ni][r] + bb, 1e4f));
          }
      }
    } else {
      const float bb = bias0[col];
#pragma unroll
      for (int mi = 0; mi < 4; mi++)
#pragma unroll
        for (int r = 0; r < 4; r++) {
          const int row = m0 + wm + mi * 16 + quad * 4 + r;
          float vv = acc[mi][ni][r] + bb;
          if (EPI == 2) {
            vv = gelu_exact(vv);
            vv += b2f(((const bf16*)residv)[(long)row * N + col]);
            ((float*)C0v)[(long)row * N + col] = finz(vv, 1e5f);
          } else {
            if (EPI == 1) vv += ((const float*)residv)[(long)row * N + col];
            const float sent = EPI == 0 ? 4e4f : 2e4f;
            ((bf16*)C0v)[(long)row * N + col] = f2b(finz(vv, sent));
          }
        }
    }
  }
}

// ---------------------------------------------------------------------------
// Flash attention v2: grid (S/256, B*H); 4 waves x 64 q-rows each.
// Q in registers; K/V^T staged in LDS (stride 72 = conflict-free b128 reads);
// softmax fully in registers (shuffle-xor, log2 domain); P via per-wave
// padded LDS round-trip. q,k: [B,H,S,64]; vt: [B,H,64,S]. Out: [B,S,D] bf16.
// ---------------------------------------------------------------------------
__global__ __launch_bounds__(256, 2)
void attn_kernel(const bf16* __restrict__ q, const bf16* __restrict__ k,
                 const bf16* __restrict__ vt, bf16* __restrict__ o) {
  __shared__ bf16 Ks[64 * 72];
  __shared__ bf16 Vs[64 * 72];
  __shared__ bf16 Pb[4][64 * 72];

  const int t = threadIdx.x, wave = t >> 6, lane = t & 63;
  const int quad = lane >> 4, ln = lane & 15;
  const int bh = blockIdx.y;
  const int q0 = blockIdx.x * 256 + wave * 64;
  const long base = (long)bh * (2048 * 64);

  // Q fragments (A-layout), resident in registers for the whole kernel
  v8s qa[4][2];
#pragma unroll
  for (int mi = 0; mi < 4; mi++)
#pragma unroll
    for (int kc = 0; kc < 2; kc++)
      qa[mi][kc] = *(const v8s*)(q + base + (long)(q0 + mi * 16 + ln) * 64 +
                                 kc * 32 + quad * 8);

  v4f accO[4][4];
  float m2[4][4], l[4][4];  // [mi][r], log2-domain max / plain-domain sum
#pragma unroll
  for (int mi = 0; mi < 4; mi++) {
#pragma unroll
    for (int ni = 0; ni < 4; ni++) accO[mi][ni] = v4f{0.f, 0.f, 0.f, 0.f};
#pragma unroll
    for (int r = 0; r < 4; r++) { m2[mi][r] = -1e30f; l[mi][r] = 0.f; }
  }
  const float cs = 0.125f * 1.44269504089f;  // scale * log2(e)

  const int e0 = t * 8, e1 = t * 8 + 2048;
  const int r0 = e0 >> 6, c0 = e0 & 63, r1 = e1 >> 6, c1 = e1 & 63;

  for (int kv0 = 0; kv0 < 2048; kv0 += 64) {
    // stage K tile [kv][64] and V^T tile [hd][kv] (register round-trip,
    // LDS rows padded to 72 elems)
    v8s ka = *(const v8s*)(k + base + (long)(kv0 + r0) * 64 + c0);
    v8s kb2 = *(const v8s*)(k + base + (long)(kv0 + r1) * 64 + c1);
    v8s va = *(const v8s*)(vt + base + (long)r0 * 2048 + kv0 + c0);
    v8s vb2 = *(const v8s*)(vt + base + (long)r1 * 2048 + kv0 + c1);
    __syncthreads();
    *(v8s*)&Ks[r0 * 72 + c0] = ka;
    *(v8s*)&Ks[r1 * 72 + c1] = kb2;
    *(v8s*)&Vs[r0 * 72 + c0] = va;
    *(v8s*)&Vs[r1 * 72 + c1] = vb2;
    __syncthreads();

    v8s kb[4][2];
#pragma unroll
    for (int ni = 0; ni < 4; ni++)
#pragma unroll
      for (int kc = 0; kc < 2; kc++)
        kb[ni][kc] = *(const v8s*)&Ks[(ni * 16 + ln) * 72 + kc * 32 + quad * 8];

#pragma unroll
    for (int mi = 0; mi < 4; mi++) {
      // S = Q K^T for this 16-row block
      v4f s[4];
#pragma unroll
      for (int ni = 0; ni < 4; ni++) {
        v4f z = v4f{0.f, 0.f, 0.f, 0.f};
        z = mfma16x16x32(qa[mi][0], kb[ni][0], z);
        s[ni] = mfma16x16x32(qa[mi][1], kb[ni][1], z);
      }
      // row max (log2 domain) via shuffle-xor over ln bits
      float rmax[4];
#pragma unroll
      for (int r = 0; r < 4; r++) {
        float v = fmaxf(fmaxf(s[0][r], s[1][r]), fmaxf(s[2][r], s[3][r])) * cs;
        v = fmaxf(v, __shfl_xor(v, 1));
        v = fmaxf(v, __shfl_xor(v, 2));
        v = fmaxf(v, __shfl_xor(v, 4));
        v = fmaxf(v, __shfl_xor(v, 8));
        rmax[r] = v;
      }
      float rsum[4];
#pragma unroll
      for (int r = 0; r < 4; r++) {
        const float mo = m2[mi][r];
        const float mn = fmaxf(mo, rmax[r]);
        const float al = exp2f(mo - mn);
        m2[mi][r] = mn;
        l[mi][r] *= al;
#pragma unroll
        for (int ni = 0; ni < 4; ni++) accO[mi][ni][r] *= al;
        rsum[r] = 0.f;
      }
      // P = exp2(S*cs - m), write to per-wave padded LDS, accumulate row sums
#pragma unroll
      for (int ni = 0; ni < 4; ni++)
#pragma unroll
        for (int r = 0; r < 4; r++) {
          float p = exp2f(s[ni][r] * cs - m2[mi][r]);
          rsum[r] += p;
          Pb[wave][(mi * 16 + quad * 4 + r) * 72 + ni * 16 + ln] = f2b(p);
        }
#pragma unroll
      for (int r = 0; r < 4; r++) {
        float v = rsum[r];
        v += __shfl_xor(v, 1);
        v += __shfl_xor(v, 2);
        v += __shfl_xor(v, 4);
        v += __shfl_xor(v, 8);
        l[mi][r] += v;
      }
    }

    // O += P @ V
    v8s vbf[4][2];
#pragma unroll
    for (int ni = 0; ni < 4; ni++)
#pragma unroll
      for (int kc = 0; kc < 2; kc++)
        vbf[ni][kc] = *(const v8s*)&Vs[(ni * 16 + ln) * 72 + kc * 32 + quad * 8];
#pragma unroll
    for (int mi = 0; mi < 4; mi++) {
      v8s pa0 = *(const v8s*)&Pb[wave][(mi * 16 + ln) * 72 + quad * 8];
      v8s pa1 = *(const v8s*)&Pb[wave][(mi * 16 + ln) * 72 + 32 + quad * 8];
#pragma unroll
      for (int ni = 0; ni < 4; ni++) {
        accO[mi][ni] = mfma16x16x32(pa0, vbf[ni][0], accO[mi][ni]);
        accO[mi][ni] = mfma16x16x32(pa1, vbf[ni][1], accO[mi][ni]);
      }
    }
  }

  // epilogue: o[b][s][h*64+hd] = accO / l
  const int b_ = bh >> 4, h_ = bh & 15;
#pragma unroll
  for (int mi = 0; mi < 4; mi++)
#pragma unroll
    for (int r = 0; r < 4; r++) {
      const int srow = q0 + mi * 16 + quad * 4 + r;
      const float inv = 1.0f / l[mi][r];
#pragma unroll
      for (int ni = 0; ni < 4; ni++) {
        const int hd = ni * 16 + ln;
        o[((long)(b_ * 2048 + srow)) * 1024 + h_ * 64 + hd] =
            f2b(finz(accO[mi][ni][r] * inv, 5000.f));
      }
    }
}

// ---------------------------------------------------------------------------
extern "C" void kernel_launch(void* const* d_in, const int* in_sizes, int n_in,
                              void* d_out, int out_size, void* d_ws,
                              size_t ws_size, hipStream_t stream) {
  const float* x   = (const float*)d_in[0];
  const float* Wq  = (const float*)d_in[1];
  const float* bq  = (const float*)d_in[2];
  const float* Wk  = (const float*)d_in[3];
  const float* bk  = (const float*)d_in[4];
  const float* Wv  = (const float*)d_in[5];
  const float* bv  = (const float*)d_in[6];
  const float* Wo  = (const float*)d_in[7];
  const float* bo  = (const float*)d_in[8];
  const float* W1  = (const float*)d_in[9];
  const float* b1  = (const float*)d_in[10];
  const float* W2  = (const float*)d_in[11];
  const float* b2  = (const float*)d_in[12];
  const float* g1  = (const float*)d_in[13];
  const float* be1 = (const float*)d_in[14];
  const float* g2  = (const float*)d_in[15];
  const float* be2 = (const float*)d_in[16];
  float* out = (float*)d_out;

  const size_t MB = 1024 * 1024;
  if (ws_size < 104 * MB) return;
  char* W = (char*)d_ws;
  bf16* wqt = (bf16*)(W + 0 * MB);
  bf16* wkt = (bf16*)(W + 2 * MB);
  bf16* wvt = (bf16*)(W + 4 * MB);
  bf16* wot = (bf16*)(W + 6 * MB);
  bf16* h   = (bf16*)(W + 8 * MB);    // LN1 out; later LN2 out
  bf16* qb  = (bf16*)(W + 24 * MB);   // dead after attn
  bf16* kb  = (bf16*)(W + 40 * MB);   // dead after attn
  bf16* vb  = (bf16*)(W + 56 * MB);   // v TRANSPOSED [B,H,64,S]; dead after attn
  bf16* ao  = (bf16*)(W + 72 * MB);   // dead after Wo-gemm
  bf16* x1  = (bf16*)(W + 88 * MB);   // live to end
  bf16* w1t = (bf16*)(W + 24 * MB);   // after attn (qb slot)
  bf16* w2t = (bf16*)(W + 32 * MB);
  bf16* tbc = (bf16*)(W + 40 * MB);   // FFN mid chunk [4096][4096]

  repack_qkv<<<4096, 256, 0, stream>>>(Wq, wqt);
  repack_qkv<<<4096, 256, 0, stream>>>(Wk, wkt);
  repack_qkv<<<4096, 256, 0, stream>>>(Wv, wvt);
  transpose_f2b<<<dim3(32, 32), 256, 0, stream>>>(Wo, wot, 1024, 1024);

  // 1) h = LN1(x)
  ln_kernel<float><<<8192, 256, 0, stream>>>(x, g1, be1, h);
  // 2) q,k,v = h @ Wqkv + b  (q,k -> [B,H,S,64]; v -> [B,H,64,S])
  gemm_bt<3><<<dim3(24, 64), 256, 0, stream>>>(h, wqt, bq, bk, bv, nullptr,
                                               qb, kb, vb, 8192, 3072, 1024);
  // 3) flash attention -> ao [B,S,D]
  attn_kernel<<<dim3(8, 64), 256, 0, stream>>>(qb, kb, vb, ao);
  // 4) x1 = x + ao @ Wo + bo
  gemm_bt<1><<<dim3(8, 64), 256, 0, stream>>>(ao, wot, bo, nullptr, nullptr, x,
                                              x1, nullptr, nullptr, 8192, 1024, 1024);
  transpose_f2b<<<dim3(128, 32), 256, 0, stream>>>(W1, w1t, 1024, 4096);
  transpose_f2b<<<dim3(32, 128), 256, 0, stream>>>(W2, w2t, 4096, 1024);
  // 5) h2 = LN2(x1)
  ln_kernel<bf16><<<8192, 256, 0, stream>>>(x1, g2, be2, h);
  // 6/7) FFN, M-chunked (2 x 4096 rows); final out FP32
  for (int c = 0; c < 2; c++) {
    const long moff = (long)c * 4096 * 1024;
    gemm_bt<0><<<dim3(32, 32), 256, 0, stream>>>(h + moff, w1t, b1, nullptr,
                                                 nullptr, nullptr, tbc, nullptr,
                                                 nullptr, 4096, 4096, 1024);
    gemm_bt<2><<<dim3(8, 32), 256, 0, stream>>>(tbc, w2t, b2, nullptr, nullptr,
                                                x1 + moff, out + moff, nullptr,
                                                nullptr, 4096, 1024, 4096);
  }
}

// Round 7
// 785.462 us; speedup vs baseline: 1.2378x; 1.1070x over previous
//
#include <hip/hip_runtime.h>
#include <hip/hip_bf16.h>
#include <cmath>

typedef __hip_bfloat16 bf16;
typedef float v4f __attribute__((ext_vector_type(4)));
typedef short v8s __attribute__((ext_vector_type(8)));   // 8 x bf16 bits
typedef short v4s __attribute__((ext_vector_type(4)));   // 4 x bf16 bits

__device__ __forceinline__ void load_lds16(const void* g, void* l) {
  __builtin_amdgcn_global_load_lds(
      (const __attribute__((address_space(1))) char*)g,
      (__attribute__((address_space(3))) char*)l, 16, 0, 0);
}
__device__ __forceinline__ v4f mfma16x16x32(v8s a, v8s b, v4f c) {
  return __builtin_amdgcn_mfma_f32_16x16x32_bf16(a, b, c, 0, 0, 0);
}
__device__ __forceinline__ v4f mfma16x16x16(v4s a, v4s b, v4f c) {
#if __has_builtin(__builtin_amdgcn_mfma_f32_16x16x16_bf16)
  return __builtin_amdgcn_mfma_f32_16x16x16_bf16(a, b, c, 0, 0, 0);
#elif __has_builtin(__builtin_amdgcn_mfma_f32_16x16x16bf16_1k)
  return __builtin_amdgcn_mfma_f32_16x16x16bf16_1k(a, b, c, 0, 0, 0);
#else
  v4f d;
  asm("v_mfma_f32_16x16x16_bf16 %0, %1, %2, %3"
      : "=v"(d) : "v"(a), "v"(b), "v"(c));
  return d;
#endif
}
__device__ __forceinline__ float b2f(bf16 x) { return __bfloat162float(x); }
__device__ __forceinline__ bf16 f2b(float x) { return __float2bfloat16(x); }
__device__ __forceinline__ ushort b2u(float x) {
  bf16 h = f2b(x);
  return *(ushort*)&h;
}
__device__ __forceinline__ float fexp2(float x) {
#if __has_builtin(__builtin_amdgcn_exp2f)
  return __builtin_amdgcn_exp2f(x);
#else
  return exp2f(x);
#endif
}
__device__ __forceinline__ float gelu_exact(float x) {
  return 0.5f * x * (1.0f + erff(x * 0.70710678118654752f));
}
__device__ __forceinline__ float finz(float v, float sent) {
  return __builtin_isfinite(v) ? v : sent;
}
__device__ __forceinline__ float u2f(ushort u) {
  return __uint_as_float(((unsigned)u) << 16);
}
__device__ __forceinline__ float4 load4f(const float* p) {
  return *(const float4*)p;
}
__device__ __forceinline__ float4 load4f(const bf16* p) {
  ushort4 u = *(const ushort4*)p;
  return make_float4(u2f(u.x), u2f(u.y), u2f(u.z), u2f(u.w));
}

// ---------------------------------------------------------------------------
// LayerNorm: one block per row of 1024, fp32 stats, bf16 out.
// ---------------------------------------------------------------------------
template <typename TI>
__global__ __launch_bounds__(256)
void ln_kernel(const TI* __restrict__ x, const float* __restrict__ g,
               const float* __restrict__ b, bf16* __restrict__ out) {
  __shared__ float red[8];
  __shared__ float stat[2];
  const int row = blockIdx.x, t = threadIdx.x;
  const int wave = t >> 6, lane = t & 63;
  float4 v = load4f(x + (long)row * 1024 + t * 4);
  float s = v.x + v.y + v.z + v.w;
  float s2 = v.x * v.x + v.y * v.y + v.z * v.z + v.w * v.w;
#pragma unroll
  for (int off = 32; off > 0; off >>= 1) {
    s += __shfl_down(s, off);
    s2 += __shfl_down(s2, off);
  }
  if (lane == 0) { red[wave * 2] = s; red[wave * 2 + 1] = s2; }
  __syncthreads();
  if (t == 0) {
    float S = red[0] + red[2] + red[4] + red[6];
    float S2 = red[1] + red[3] + red[5] + red[7];
    float mean = S * (1.0f / 1024.0f);
    float var = S2 * (1.0f / 1024.0f) - mean * mean;
    stat[0] = mean;
    stat[1] = rsqrtf(var + 1e-5f);
  }
  __syncthreads();
  const float mean = stat[0], rs = stat[1];
  bf16* orow = out + (long)row * 1024;
  const int c = t * 4;
  float4 gg = *(const float4*)(g + c);
  float4 bb = *(const float4*)(b + c);
  orow[c + 0] = f2b(finz((v.x - mean) * rs * gg.x + bb.x, 3000.f));
  orow[c + 1] = f2b(finz((v.y - mean) * rs * gg.y + bb.y, 3000.f));
  orow[c + 2] = f2b(finz((v.z - mean) * rs * gg.z + bb.z, 3000.f));
  orow[c + 3] = f2b(finz((v.w - mean) * rs * gg.w + bb.w, 3000.f));
}

// ---------------------------------------------------------------------------
// Repack Wq/Wk/Wv fp32 [H=16, D=1024, HD=64] -> bf16 Wt[n=h*64+kk][d]
// ---------------------------------------------------------------------------
__global__ __launch_bounds__(256)
void repack_qkv(const float* __restrict__ w, bf16* __restrict__ wt) {
  long i = (long)blockIdx.x * 256 + threadIdx.x;
  int n = (int)(i >> 10), d = (int)(i & 1023);
  int h = n >> 6, kk = n & 63;
  wt[i] = f2b(w[((long)h * 1024 + d) * 64 + kk]);
}

// ---------------------------------------------------------------------------
// Tiled transpose fp32 -> bf16: out[c*R + r] = in[r*C + c]
// ---------------------------------------------------------------------------
__global__ __launch_bounds__(256)
void transpose_f2b(const float* __restrict__ in, bf16* __restrict__ out,
                   int R, int C) {
  __shared__ float tile[32][33];
  const int tx = threadIdx.x & 31, ty = threadIdx.x >> 5;
  const int r0 = blockIdx.y * 32, c0 = blockIdx.x * 32;
#pragma unroll
  for (int i = ty; i < 32; i += 8) tile[i][tx] = in[(long)(r0 + i) * C + c0 + tx];
  __syncthreads();
#pragma unroll
  for (int i = ty; i < 32; i += 8)
    out[(long)(c0 + i) * R + r0 + tx] = f2b(tile[tx][i]);
}

// ---------------------------------------------------------------------------
// GEMM C[M,N] = A[M,K] @ Bt[N,K]^T (128x128, BK=32, async global_load_lds).
// EPI: 0=+bias (bf16)  1=+bias+fp32 resid (bf16)  2=gelu+bf16 resid (FP32)
//      3=QKV scatter: q (PRE-SCALED by 0.125*log2e), k -> [B,H,S,64];
//        v -> TRANSPOSED [B,H,64,S]
// ---------------------------------------------------------------------------
template <int EPI>
__global__ __launch_bounds__(256)
void gemm_bt(const bf16* __restrict__ A, const bf16* __restrict__ Bt,
             const float* __restrict__ bias0, const float* __restrict__ bias1,
             const float* __restrict__ bias2, const void* __restrict__ residv,
             void* __restrict__ C0v, bf16* __restrict__ C1, bf16* __restrict__ C2v,
             int M, int N, int K) {
  __shared__ bf16 As[128 * 32];
  __shared__ bf16 Bs[128 * 32];
  const int t = threadIdx.x;
  const int wave = t >> 6, lane = t & 63, quad = lane >> 4, ln = lane & 15;
  const int m0 = blockIdx.y * 128, n0 = blockIdx.x * 128;
  const int wm = (wave >> 1) * 64, wn = (wave & 1) * 64;

  v4f acc[4][4];
#pragma unroll
  for (int i = 0; i < 4; i++)
#pragma unroll
    for (int j = 0; j < 4; j++) acc[i][j] = v4f{0.f, 0.f, 0.f, 0.f};

  const int e0 = t * 8, e1 = t * 8 + 2048;
  const int ra0 = e0 >> 5, ca0 = e0 & 31, ra1 = e1 >> 5, ca1 = e1 & 31;
  const bf16* Ab = A + (long)m0 * K;
  const bf16* Bb = Bt + (long)n0 * K;

  for (int k0 = 0; k0 < K; k0 += 32) {
    __syncthreads();
    load_lds16(Ab + (long)ra0 * K + k0 + ca0, &As[e0]);
    load_lds16(Ab + (long)ra1 * K + k0 + ca1, &As[e1]);
    load_lds16(Bb + (long)ra0 * K + k0 + ca0, &Bs[e0]);
    load_lds16(Bb + (long)ra1 * K + k0 + ca1, &Bs[e1]);
    __syncthreads();
    v8s af[4], bfr[4];
#pragma unroll
    for (int mi = 0; mi < 4; mi++)
      af[mi] = *(const v8s*)&As[(wm + mi * 16 + ln) * 32 + quad * 8];
#pragma unroll
    for (int ni = 0; ni < 4; ni++)
      bfr[ni] = *(const v8s*)&Bs[(wn + ni * 16 + ln) * 32 + quad * 8];
#pragma unroll
    for (int mi = 0; mi < 4; mi++)
#pragma unroll
      for (int ni = 0; ni < 4; ni++)
        acc[mi][ni] = mfma16x16x32(af[mi], bfr[ni], acc[mi][ni]);
  }

#pragma unroll
  for (int ni = 0; ni < 4; ni++) {
    const int col = n0 + wn + ni * 16 + ln;
    if (EPI == 3) {
      const int proj = col >> 10, w = col & 1023;
      const float* bp = proj == 0 ? bias0 : (proj == 1 ? bias1 : bias2);
      const float bb = bp[w];
      const int hidx = w >> 6, hd = w & 63;
      if (proj == 2) {
        // v transposed: [b*16+h][hd][2048], ushort4-packed along s
#pragma unroll
        for (int mi = 0; mi < 4; mi++) {
          const int row0 = m0 + wm + mi * 16 + quad * 4;
          const int b_ = row0 >> 11, s = row0 & 2047;
          ushort4 pk;
          pk.x = b2u(finz(acc[mi][ni][0] + bb, 1e4f));
          pk.y = b2u(finz(acc[mi][ni][1] + bb, 1e4f));
          pk.z = b2u(finz(acc[mi][ni][2] + bb, 1e4f));
          pk.w = b2u(finz(acc[mi][ni][3] + bb, 1e4f));
          *(ushort4*)((ushort*)C2v +
                      (((long)(b_ * 16 + hidx)) * 64 + hd) * 2048 + s) = pk;
        }
      } else {
        bf16* op = proj == 0 ? (bf16*)C0v : C1;
        const float sc = proj == 0 ? 0.18033688f : 1.0f;  // 0.125*log2(e)
#pragma unroll
        for (int mi = 0; mi < 4; mi++)
#pragma unroll
          for (int r = 0; r < 4; r++) {
            const int row = m0 + wm + mi * 16 + quad * 4 + r;
            const int b_ = row >> 11, s = row & 2047;
            op[(((long)(b_ * 16 + hidx)) * 2048 + s) * 64 + hd] =
                f2b(finz((acc[mi][ni][r] + bb) * sc, 1e4f));
          }
      }
    } else {
      const float bb = bias0[col];
#pragma unroll
      for (int mi = 0; mi < 4; mi++)
#pragma unroll
        for (int r = 0; r < 4; r++) {
          const int row = m0 + wm + mi * 16 + quad * 4 + r;
          float vv = acc[mi][ni][r] + bb;
          if (EPI == 2) {
            vv = gelu_exact(vv);
            vv += b2f(((const bf16*)residv)[(long)row * N + col]);
            ((float*)C0v)[(long)row * N + col] = finz(vv, 1e5f);
          } else {
            if (EPI == 1) vv += ((const float*)residv)[(long)row * N + col];
            const float sent = EPI == 0 ? 4e4f : 2e4f;
            ((bf16*)C0v)[(long)row * N + col] = f2b(finz(vv, sent));
          }
        }
    }
  }
}

// ---------------------------------------------------------------------------
// Flash attention v3 (register S^T): grid (8, B*H); 4 waves x 64 q-rows.
// S^T = K·Q^T so each softmax row lives in ONE lane-column (2 shuffles/row
// block). P^T C-layout == 16x16x16 B-operand layout -> PV directly from
// registers (no P LDS round-trip). No LDS at all; K/V^T frags from global
// (L2-resident), register double-buffered. q pre-scaled by 0.125*log2e.
// q,k: [B,H,S,64]; vt: [B,H,64,S]. Out: [B,S,D] bf16.
// ---------------------------------------------------------------------------
__global__ __launch_bounds__(256, 2)
void attn_kernel(const bf16* __restrict__ q, const bf16* __restrict__ k,
                 const bf16* __restrict__ vt, bf16* __restrict__ o) {
  const int t = threadIdx.x, wave = t >> 6, lane = t & 63;
  const int quad = lane >> 4, ln = lane & 15;
  const int bh = blockIdx.y;
  const int q0 = blockIdx.x * 256 + wave * 64;
  const long base = (long)bh * (2048 * 64);

  // Q as B-operand frags (register-resident): Q[q0+mi*16+ln][kc*32+quad*8+j]
  v8s qf[4][2];
#pragma unroll
  for (int mi = 0; mi < 4; mi++)
#pragma unroll
    for (int kc = 0; kc < 2; kc++)
      qf[mi][kc] = *(const v8s*)(q + base + (long)(q0 + mi * 16 + ln) * 64 +
                                 kc * 32 + quad * 8);

  v4f accO[4][4];  // [mi][nh]: O^T tile, col=ln (q-row), row=quad*4+r (hd)
  float m2[4], l[4];
#pragma unroll
  for (int mi = 0; mi < 4; mi++) {
#pragma unroll
    for (int nh = 0; nh < 4; nh++) accO[mi][nh] = v4f{0.f, 0.f, 0.f, 0.f};
    m2[mi] = -1e30f;
    l[mi] = 0.f;
  }

  // fragment double-buffer (registers)
  v8s ka[4][2], kan[4][2];
  v4s va[4][4], van[4][4];
#pragma unroll
  for (int ni = 0; ni < 4; ni++)
#pragma unroll
    for (int kc = 0; kc < 2; kc++)
      ka[ni][kc] = *(const v8s*)(k + base + (long)(ni * 16 + ln) * 64 +
                                 kc * 32 + quad * 8);
#pragma unroll
  for (int nh = 0; nh < 4; nh++)
#pragma unroll
    for (int ni = 0; ni < 4; ni++)
      va[nh][ni] = *(const v4s*)(vt + base + (long)(nh * 16 + ln) * 2048 +
                                 ni * 16 + quad * 4);

  for (int kv0 = 0; kv0 < 2048; kv0 += 64) {
    const int kvn = (kv0 + 64 < 2048) ? kv0 + 64 : kv0;
    // prefetch next tile's fragments
#pragma unroll
    for (int ni = 0; ni < 4; ni++)
#pragma unroll
      for (int kc = 0; kc < 2; kc++)
        kan[ni][kc] = *(const v8s*)(k + base +
                                    (long)(kvn + ni * 16 + ln) * 64 +
                                    kc * 32 + quad * 8);
#pragma unroll
    for (int nh = 0; nh < 4; nh++)
#pragma unroll
      for (int ni = 0; ni < 4; ni++)
        van[nh][ni] = *(const v4s*)(vt + base + (long)(nh * 16 + ln) * 2048 +
                                    kvn + ni * 16 + quad * 4);

#pragma unroll
    for (int mi = 0; mi < 4; mi++) {
      // S^T tiles: st[ni] at lane: key = ni*16 + quad*4 + r, qrow = mi*16+ln
      v4f st[4];
#pragma unroll
      for (int ni = 0; ni < 4; ni++) {
        v4f z = v4f{0.f, 0.f, 0.f, 0.f};
        z = mfma16x16x32(ka[ni][0], qf[mi][0], z);
        st[ni] = mfma16x16x32(ka[ni][1], qf[mi][1], z);
      }
      // row max: in-lane over 16 + 2 cross-quad shuffles
      float mx = st[0][0];
#pragma unroll
      for (int ni = 0; ni < 4; ni++)
#pragma unroll
        for (int r = 0; r < 4; r++) mx = fmaxf(mx, st[ni][r]);
      mx = fmaxf(mx, __shfl_xor(mx, 16));
      mx = fmaxf(mx, __shfl_xor(mx, 32));
      const float mo = m2[mi];
      const float mn = fmaxf(mo, mx);
      const float al = fexp2(mo - mn);
      m2[mi] = mn;
      l[mi] *= al;
#pragma unroll
      for (int nh = 0; nh < 4; nh++)
#pragma unroll
        for (int r = 0; r < 4; r++) accO[mi][nh][r] *= al;
      // P^T = exp2(S^T - m) packed straight into 16x16x16 B-frags
      float rs = 0.f;
      v4s pf[4];
#pragma unroll
      for (int ni = 0; ni < 4; ni++) {
        v4s p4;
#pragma unroll
        for (int r = 0; r < 4; r++) {
          float p = fexp2(st[ni][r] - mn);
          rs += p;
          p4[r] = (short)b2u(p);
        }
        pf[ni] = p4;
      }
      rs += __shfl_xor(rs, 16);
      rs += __shfl_xor(rs, 32);
      l[mi] += rs;
      // O^T += V^T · P^T  (A = V^T frag, B = P^T frag)
#pragma unroll
      for (int nh = 0; nh < 4; nh++)
#pragma unroll
        for (int ni = 0; ni < 4; ni++)
          accO[mi][nh] = mfma16x16x16(va[nh][ni], pf[ni], accO[mi][nh]);
    }
    // rotate double-buffer
#pragma unroll
    for (int ni = 0; ni < 4; ni++)
#pragma unroll
      for (int kc = 0; kc < 2; kc++) ka[ni][kc] = kan[ni][kc];
#pragma unroll
    for (int nh = 0; nh < 4; nh++)
#pragma unroll
      for (int ni = 0; ni < 4; ni++) va[nh][ni] = van[nh][ni];
  }

  // epilogue: o[b][s=q0+mi*16+ln][h*64 + nh*16+quad*4+r] = accO/l
  const int b_ = bh >> 4, h_ = bh & 15;
#pragma unroll
  for (int mi = 0; mi < 4; mi++) {
    const float inv = 1.0f / l[mi];
    const int s = q0 + mi * 16 + ln;
#pragma unroll
    for (int nh = 0; nh < 4; nh++) {
      ushort4 pk;
      pk.x = b2u(finz(accO[mi][nh][0] * inv, 5000.f));
      pk.y = b2u(finz(accO[mi][nh][1] * inv, 5000.f));
      pk.z = b2u(finz(accO[mi][nh][2] * inv, 5000.f));
      pk.w = b2u(finz(accO[mi][nh][3] * inv, 5000.f));
      *(ushort4*)((ushort*)o + ((long)(b_ * 2048 + s)) * 1024 + h_ * 64 +
                  nh * 16 + quad * 4) = pk;
    }
  }
}

// ---------------------------------------------------------------------------
extern "C" void kernel_launch(void* const* d_in, const int* in_sizes, int n_in,
                              void* d_out, int out_size, void* d_ws,
                              size_t ws_size, hipStream_t stream) {
  const float* x   = (const float*)d_in[0];
  const float* Wq  = (const float*)d_in[1];
  const float* bq  = (const float*)d_in[2];
  const float* Wk  = (const float*)d_in[3];
  const float* bk  = (const float*)d_in[4];
  const float* Wv  = (const float*)d_in[5];
  const float* bv  = (const float*)d_in[6];
  const float* Wo  = (const float*)d_in[7];
  const float* bo  = (const float*)d_in[8];
  const float* W1  = (const float*)d_in[9];
  const float* b1  = (const float*)d_in[10];
  const float* W2  = (const float*)d_in[11];
  const float* b2  = (const float*)d_in[12];
  const float* g1  = (const float*)d_in[13];
  const float* be1 = (const float*)d_in[14];
  const float* g2  = (const float*)d_in[15];
  const float* be2 = (const float*)d_in[16];
  float* out = (float*)d_out;

  const size_t MB = 1024 * 1024;
  if (ws_size < 104 * MB) return;
  char* W = (char*)d_ws;
  bf16* wqt = (bf16*)(W + 0 * MB);
  bf16* wkt = (bf16*)(W + 2 * MB);
  bf16* wvt = (bf16*)(W + 4 * MB);
  bf16* wot = (bf16*)(W + 6 * MB);
  bf16* h   = (bf16*)(W + 8 * MB);    // LN1 out; later LN2 out
  bf16* qb  = (bf16*)(W + 24 * MB);   // dead after attn
  bf16* kb  = (bf16*)(W + 40 * MB);   // dead after attn
  bf16* vb  = (bf16*)(W + 56 * MB);   // v TRANSPOSED [B,H,64,S]; dead after attn
  bf16* ao  = (bf16*)(W + 72 * MB);   // dead after Wo-gemm
  bf16* x1  = (bf16*)(W + 88 * MB);   // live to end
  bf16* w1t = (bf16*)(W + 24 * MB);   // after attn (qb slot)
  bf16* w2t = (bf16*)(W + 32 * MB);
  bf16* tbc = (bf16*)(W + 40 * MB);   // FFN mid chunk [4096][4096]

  repack_qkv<<<4096, 256, 0, stream>>>(Wq, wqt);
  repack_qkv<<<4096, 256, 0, stream>>>(Wk, wkt);
  repack_qkv<<<4096, 256, 0, stream>>>(Wv, wvt);
  transpose_f2b<<<dim3(32, 32), 256, 0, stream>>>(Wo, wot, 1024, 1024);

  // 1) h = LN1(x)
  ln_kernel<float><<<8192, 256, 0, stream>>>(x, g1, be1, h);
  // 2) q,k,v = h @ Wqkv + b  (q scaled; q,k -> [B,H,S,64]; v -> [B,H,64,S])
  gemm_bt<3><<<dim3(24, 64), 256, 0, stream>>>(h, wqt, bq, bk, bv, nullptr,
                                               qb, kb, vb, 8192, 3072, 1024);
  // 3) flash attention -> ao [B,S,D]
  attn_kernel<<<dim3(8, 64), 256, 0, stream>>>(qb, kb, vb, ao);
  // 4) x1 = x + ao @ Wo + bo
  gemm_bt<1><<<dim3(8, 64), 256, 0, stream>>>(ao, wot, bo, nullptr, nullptr, x,
                                              x1, nullptr, nullptr, 8192, 1024, 1024);
  transpose_f2b<<<dim3(128, 32), 256, 0, stream>>>(W1, w1t, 1024, 4096);
  transpose_f2b<<<dim3(32, 128), 256, 0, stream>>>(W2, w2t, 4096, 1024);
  // 5) h2 = LN2(x1)
  ln_kernel<bf16><<<8192, 256, 0, stream>>>(x1, g2, be2, h);
  // 6/7) FFN, M-chunked (2 x 4096 rows); final out FP32
  for (int c = 0; c < 2; c++) {
    const long moff = (long)c * 4096 * 1024;
    gemm_bt<0><<<dim3(32, 32), 256, 0, stream>>>(h + moff, w1t, b1, nullptr,
                                                 nullptr, nullptr, tbc, nullptr,
                                                 nullptr, 4096, 4096, 1024);
    gemm_bt<2><<<dim3(8, 32), 256, 0, stream>>>(tbc, w2t, b2, nullptr, nullptr,
                                                x1 + moff, out + moff, nullptr,
                                                nullptr, 4096, 1024, 4096);
  }
}